// Round 4
// baseline (192.472 us; speedup 1.0000x reference)
//
#include <hip/hip_runtime.h>
#include <hip/hip_bf16.h>

typedef __attribute__((ext_vector_type(8))) short short8;
typedef __attribute__((ext_vector_type(4))) short short4v;
typedef __attribute__((ext_vector_type(4))) float f32x4;

#define S_LEN 2048
#define DM 1024
#define NH 16
#define HD 64

__device__ __forceinline__ short f2b(float f) {
    __hip_bfloat16 h = __float2bfloat16(f);
    return *reinterpret_cast<short*>(&h);
}

__device__ __forceinline__ void gload_lds16(const void* g, void* l) {
    __builtin_amdgcn_global_load_lds(
        (const __attribute__((address_space(1))) unsigned int*)g,
        (__attribute__((address_space(3))) unsigned int*)l, 16, 0, 0);
}

// ---------------- convert x (fp32 -> bf16) ----------------
__global__ void k_convert_x(const float* __restrict__ x, short* __restrict__ xb) {
    size_t i = ((size_t)blockIdx.x * blockDim.x + threadIdx.x) * 4;
    f32x4 v = *reinterpret_cast<const f32x4*>(x + i);
    short4v o;
    for (int e = 0; e < 4; e++) o[e] = f2b(v[e]);
    *reinterpret_cast<short4v*>(xb + i) = o;
}

// ---------------- transpose + convert W (fp32 [K][N] -> bf16 [N][K]) ----------------
__global__ void k_transpose_w(const float* __restrict__ W, short* __restrict__ Wt) {
    __shared__ float tile[32][33];
    int tx = threadIdx.x, ty = threadIdx.y;
    int nb = blockIdx.x * 32, kb = blockIdx.y * 32;
    for (int i = 0; i < 4; i++)
        tile[ty + i * 8][tx] = W[(size_t)(kb + ty + i * 8) * DM + nb + tx];
    __syncthreads();
    for (int i = 0; i < 4; i++)
        Wt[(size_t)(nb + ty + i * 8) * DM + kb + tx] = f2b(tile[tx][ty + i * 8]);
}

// ---------------- fused QKV GEMM (m97 global_load_lds staging) ----------------
// Q is scaled by (1/sqrt(1024)) * log2(e) so attention softmax can use exp2.
__global__ __launch_bounds__(256) void k_gemm_qkv(
    const short* __restrict__ xb,
    const short* __restrict__ Wqt, const short* __restrict__ Wkt, const short* __restrict__ Wvt,
    const float* __restrict__ bq, const float* __restrict__ bk, const float* __restrict__ bv,
    short* __restrict__ Qb, short* __restrict__ Kb, short* __restrict__ Vb,
    float* __restrict__ pK, float* __restrict__ pV)
{
    __shared__ alignas(16) short As[128][64];
    __shared__ alignas(16) short Bs[128][64];
    const int z = blockIdx.z;
    const short* Wt  = (z == 0) ? Wqt : (z == 1) ? Wkt : Wvt;
    const float* bias = (z == 0) ? bq : (z == 1) ? bk : bv;
    short* Cb = (z == 0) ? Qb : (z == 1) ? Kb : Vb;
    float* Cf = (z == 1) ? pK : pV;
    const int t = threadIdx.x;
    const int brow = blockIdx.y * 128, bcol = blockIdx.x * 128;
    const int w = t >> 6, l = t & 63;
    const int wr = w >> 1, wc = w & 1;
    const int lr = l & 15, lg = l >> 4;
    const int srow = t >> 3, scol = (t & 7) * 8;   // staging row/col for this thread
    f32x4 acc[4][4];
    for (int m = 0; m < 4; m++) for (int n = 0; n < 4; n++) acc[m][n] = (f32x4)0.0f;

    for (int k0 = 0; k0 < DM; k0 += 64) {
        __syncthreads();
#pragma unroll
        for (int i = 0; i < 4; i++) {
            int idx = i * 256 + t;
            gload_lds16(&xb[(size_t)(brow + i * 32 + srow) * DM + k0 + scol], &As[0][0] + idx * 8);
            gload_lds16(&Wt[(size_t)(bcol + i * 32 + srow) * DM + k0 + scol], &Bs[0][0] + idx * 8);
        }
        __syncthreads();
#pragma unroll
        for (int ks = 0; ks < 2; ks++) {
            short8 a[4], bb[4];
            const int kk = ks * 32 + lg * 8;
#pragma unroll
            for (int m = 0; m < 4; m++)
                a[m] = *reinterpret_cast<const short8*>(&As[wr * 64 + m * 16 + lr][kk]);
#pragma unroll
            for (int n = 0; n < 4; n++)
                bb[n] = *reinterpret_cast<const short8*>(&Bs[wc * 64 + n * 16 + lr][kk]);
#pragma unroll
            for (int m = 0; m < 4; m++)
#pragma unroll
                for (int n = 0; n < 4; n++)
                    acc[m][n] = __builtin_amdgcn_mfma_f32_16x16x32_bf16(a[m], bb[n], acc[m][n], 0, 0, 0);
        }
    }
    for (int m = 0; m < 4; m++)
        for (int n = 0; n < 4; n++) {
            int row = brow + wr * 64 + m * 16 + lg * 4;
            int col = bcol + wc * 64 + n * 16 + lr;
            float bv_ = bias[col];
            for (int r = 0; r < 4; r++) {
                int rr = row + r;
                float v = acc[m][n][r] + bv_;
                if (z == 0) {
                    Cb[(size_t)rr * DM + col] = f2b(v * 0.0450842200575152f);  // 1/32 * log2(e)
                } else {
                    Cb[(size_t)rr * DM + col] = f2b(v);
                    int b_ = rr >> 11, sI = rr & 2047, hI = col >> 6, dh = col & 63;
                    Cf[(((size_t)(b_ * NH + hI)) * S_LEN + sI) * HD + dh] = v;
                }
            }
        }
}

// ---------------- final GEMM: out = attn @ Wo + bo (m97 staging) ----------------
__global__ __launch_bounds__(256) void k_gemm_o(
    const short* __restrict__ Ab, const short* __restrict__ Wot,
    const float* __restrict__ bo, float* __restrict__ out)
{
    __shared__ alignas(16) short As[128][64];
    __shared__ alignas(16) short Bs[128][64];
    const int t = threadIdx.x;
    const int brow = blockIdx.y * 128, bcol = blockIdx.x * 128;
    const int w = t >> 6, l = t & 63;
    const int wr = w >> 1, wc = w & 1;
    const int lr = l & 15, lg = l >> 4;
    const int srow = t >> 3, scol = (t & 7) * 8;
    f32x4 acc[4][4];
    for (int m = 0; m < 4; m++) for (int n = 0; n < 4; n++) acc[m][n] = (f32x4)0.0f;

    for (int k0 = 0; k0 < DM; k0 += 64) {
        __syncthreads();
#pragma unroll
        for (int i = 0; i < 4; i++) {
            int idx = i * 256 + t;
            gload_lds16(&Ab[(size_t)(brow + i * 32 + srow) * DM + k0 + scol], &As[0][0] + idx * 8);
            gload_lds16(&Wot[(size_t)(bcol + i * 32 + srow) * DM + k0 + scol], &Bs[0][0] + idx * 8);
        }
        __syncthreads();
#pragma unroll
        for (int ks = 0; ks < 2; ks++) {
            short8 a[4], bb[4];
            const int kk = ks * 32 + lg * 8;
#pragma unroll
            for (int m = 0; m < 4; m++)
                a[m] = *reinterpret_cast<const short8*>(&As[wr * 64 + m * 16 + lr][kk]);
#pragma unroll
            for (int n = 0; n < 4; n++)
                bb[n] = *reinterpret_cast<const short8*>(&Bs[wc * 64 + n * 16 + lr][kk]);
#pragma unroll
            for (int m = 0; m < 4; m++)
#pragma unroll
                for (int n = 0; n < 4; n++)
                    acc[m][n] = __builtin_amdgcn_mfma_f32_16x16x32_bf16(a[m], bb[n], acc[m][n], 0, 0, 0);
        }
    }
    for (int m = 0; m < 4; m++)
        for (int n = 0; n < 4; n++) {
            int row = brow + wr * 64 + m * 16 + lg * 4;
            int col = bcol + wc * 64 + n * 16 + lr;
            float bv_ = bo[col];
            for (int r = 0; r < 4; r++)
                out[(size_t)(row + r) * DM + col] = acc[m][n][r] + bv_;
        }
}

// ---------------- causal flash attention ----------------
// grid 1024, one q-tile per block, descending-qt dispatch for load balance.
// bh = bid&31 keeps 4 (b,h) per XCD. R3-proven math; exp2-domain scores; defer-max.
__global__ __launch_bounds__(256, 4) void k_attn(
    const short* __restrict__ Qb, const short* __restrict__ Kb,
    const short* __restrict__ Vb, short* __restrict__ Ab)
{
    __shared__ alignas(16) short Vt[64][72];
    __shared__ alignas(16) short Pl[4][16][72];
    const int bid = blockIdx.x;
    const int qt = 31 - (bid >> 5);           // long blocks dispatch first
    const int bh = bid & 31;
    const int h = bh & 15, b = bh >> 4;
    const int t = threadIdx.x, w = t >> 6, l = t & 63;
    const int lr = l & 15, lg = l >> 4;
    const size_t base = (size_t)b * S_LEN * DM + (size_t)h * HD;
    const short* Qp = Qb + base;
    const short* Kp = Kb + base;
    const short* Vp = Vb + base;

    const int kk0 = t >> 3, d00 = (t & 7) * 8;
    const int kk1 = 32 + (t >> 3);

    const int qbase = qt * 64 + w * 16;
    short8 qf0 = *reinterpret_cast<const short8*>(Qp + (size_t)(qbase + lr) * DM + lg * 8);
    short8 qf1 = *reinterpret_cast<const short8*>(Qp + (size_t)(qbase + lr) * DM + 32 + lg * 8);
    f32x4 o[4];
    for (int dg = 0; dg < 4; dg++) o[dg] = (f32x4)0.0f;
    float mrun[4], lrun[4];
    for (int r = 0; r < 4; r++) { mrun[r] = -INFINITY; lrun[r] = 0.0f; }

    // prologue: prefetch tile 0 (V rows + K fragments) into registers
    short8 vr0 = *reinterpret_cast<const short8*>(Vp + (size_t)kk0 * DM + d00);
    short8 vr1 = *reinterpret_cast<const short8*>(Vp + (size_t)kk1 * DM + d00);
    short8 vn0 = vr0, vn1 = vr1;
    short8 kc[2][4];
#pragma unroll
    for (int ks = 0; ks < 2; ks++)
#pragma unroll
        for (int cg = 0; cg < 4; cg++)
            kc[ks][cg] = *reinterpret_cast<const short8*>(
                Kp + (size_t)(cg * 16 + lr) * DM + ks * 32 + lg * 8);

    for (int j = 0; j <= qt; ++j) {
        const int kbase = j * 64;
        __syncthreads();
#pragma unroll
        for (int e = 0; e < 8; e++) {     // swizzled-transposed V scatter (R3-proven)
            int row = d00 + e;
            int sw = (row >> 3) & 7;
            Vt[row][(((kk0 >> 3) ^ sw) << 3) | (kk0 & 7)] = vr0[e];
            Vt[row][(((kk1 >> 3) ^ sw) << 3) | (kk1 & 7)] = vr1[e];
        }
        __syncthreads();
        if (j < qt) {
            const int kb2 = kbase + 64;
            vn0 = *reinterpret_cast<const short8*>(Vp + (size_t)(kb2 + kk0) * DM + d00);
            vn1 = *reinterpret_cast<const short8*>(Vp + (size_t)(kb2 + kk1) * DM + d00);
        }
        // ---- QK^T ----
        f32x4 s[4];
#pragma unroll
        for (int cg = 0; cg < 4; cg++) s[cg] = (f32x4)0.0f;
#pragma unroll
        for (int ks = 0; ks < 2; ks++) {
            const short8 qf = ks ? qf1 : qf0;
#pragma unroll
            for (int cg = 0; cg < 4; cg++)
                s[cg] = __builtin_amdgcn_mfma_f32_16x16x32_bf16(qf, kc[ks][cg], s[cg], 0, 0, 0);
        }
        if (j < qt) {
            const int kb2 = kbase + 64;
#pragma unroll
            for (int ks = 0; ks < 2; ks++)
#pragma unroll
                for (int cg = 0; cg < 4; cg++)
                    kc[ks][cg] = *reinterpret_cast<const short8*>(
                        Kp + (size_t)(kb2 + cg * 16 + lr) * DM + ks * 32 + lg * 8);
        }
        if (j == qt) {  // causal mask on diagonal tile
#pragma unroll
            for (int cg = 0; cg < 4; cg++)
#pragma unroll
                for (int r = 0; r < 4; r++) {
                    int key = kbase + cg * 16 + lr;
                    int q   = qbase + lg * 4 + r;
                    if (key > q) s[cg][r] = -INFINITY;
                }
        }
        // ---- online softmax in exp2 domain (scores pre-scaled by log2e) ----
        float vmax[4];
#pragma unroll
        for (int r = 0; r < 4; r++) {
            float v = fmaxf(fmaxf(s[0][r], s[1][r]), fmaxf(s[2][r], s[3][r]));
#pragma unroll
            for (int mk = 1; mk < 16; mk <<= 1) v = fmaxf(v, __shfl_xor(v, mk, 16));
            vmax[r] = v;
        }
        bool ok = true;
#pragma unroll
        for (int r = 0; r < 4; r++) ok = ok && (vmax[r] - mrun[r] <= 8.0f);
        if (!__all(ok)) {   // rescale only when the running max grew materially (T13)
            float scl[4];
#pragma unroll
            for (int r = 0; r < 4; r++) {
                float mn = fmaxf(mrun[r], vmax[r]);
                scl[r] = exp2f(mrun[r] - mn);
                mrun[r] = mn;
                lrun[r] *= scl[r];
            }
#pragma unroll
            for (int dg = 0; dg < 4; dg++)
#pragma unroll
                for (int r = 0; r < 4; r++) o[dg][r] *= scl[r];
        }
        float rs[4] = {0.f, 0.f, 0.f, 0.f};
#pragma unroll
        for (int cg = 0; cg < 4; cg++)
#pragma unroll
            for (int r = 0; r < 4; r++) {
                float p = exp2f(s[cg][r] - mrun[r]);
                s[cg][r] = p;
                rs[r] += p;
            }
#pragma unroll
        for (int r = 0; r < 4; r++) {
            float v = rs[r];
#pragma unroll
            for (int mk = 1; mk < 16; mk <<= 1) v += __shfl_xor(v, mk, 16);
            lrun[r] += v;
        }
        // ---- P -> LDS (C/D layout) -> A-fragments ----
#pragma unroll
        for (int cg = 0; cg < 4; cg++)
#pragma unroll
            for (int r = 0; r < 4; r++)
                Pl[w][lg * 4 + r][cg * 16 + lr] = f2b(s[cg][r]);
        short8 pf0 = *reinterpret_cast<const short8*>(&Pl[w][lr][lg * 8]);
        short8 pf1 = *reinterpret_cast<const short8*>(&Pl[w][lr][32 + lg * 8]);
        // ---- PV from swizzled Vt ----
#pragma unroll
        for (int ks = 0; ks < 2; ks++) {
            const short8 pf = ks ? pf1 : pf0;
#pragma unroll
            for (int dg = 0; dg < 4; dg++) {
                int row = dg * 16 + lr;
                int g2 = (ks * 4 + lg) ^ ((row >> 3) & 7);
                short8 vf = *reinterpret_cast<const short8*>(&Vt[row][g2 * 8]);
                o[dg] = __builtin_amdgcn_mfma_f32_16x16x32_bf16(pf, vf, o[dg], 0, 0, 0);
            }
        }
        vr0 = vn0; vr1 = vn1;
    }
    short* Ap = Ab + base;
#pragma unroll
    for (int dg = 0; dg < 4; dg++)
#pragma unroll
        for (int r = 0; r < 4; r++) {
            int q = qbase + lg * 4 + r;
            float v = o[dg][r] / lrun[r];
            Ap[(size_t)q * DM + dg * 16 + lr] = f2b(v);
        }
}

extern "C" void kernel_launch(void* const* d_in, const int* in_sizes, int n_in,
                              void* d_out, int out_size, void* d_ws, size_t ws_size,
                              hipStream_t stream) {
    const float* x  = (const float*)d_in[0];
    const float* Wq = (const float*)d_in[1];
    const float* bq = (const float*)d_in[2];
    const float* Wk = (const float*)d_in[3];
    const float* bk = (const float*)d_in[4];
    const float* Wv = (const float*)d_in[5];
    const float* bv = (const float*)d_in[6];
    const float* Wo = (const float*)d_in[7];
    const float* bo = (const float*)d_in[8];

    float* out = (float*)d_out;
    float* presentK = out + (size_t)4194304;
    float* presentV = presentK + (size_t)4194304;

    char* ws = (char*)d_ws;
    short* xb  = (short*)(ws);
    short* Wqt = (short*)(ws + ((size_t)8  << 20));
    short* Wkt = (short*)(ws + ((size_t)10 << 20));
    short* Wvt = (short*)(ws + ((size_t)12 << 20));
    short* Wot = (short*)(ws + ((size_t)14 << 20));
    short* Qb  = (short*)(ws + ((size_t)16 << 20));
    short* Kb  = (short*)(ws + ((size_t)24 << 20));
    short* Vb  = (short*)(ws + ((size_t)32 << 20));
    short* Ab  = (short*)(ws + ((size_t)40 << 20));

    k_convert_x<<<dim3(4096), dim3(256), 0, stream>>>(x, xb);
    k_transpose_w<<<dim3(32, 32), dim3(32, 8), 0, stream>>>(Wq, Wqt);
    k_transpose_w<<<dim3(32, 32), dim3(32, 8), 0, stream>>>(Wk, Wkt);
    k_transpose_w<<<dim3(32, 32), dim3(32, 8), 0, stream>>>(Wv, Wvt);
    k_transpose_w<<<dim3(32, 32), dim3(32, 8), 0, stream>>>(Wo, Wot);
    k_gemm_qkv<<<dim3(8, 32, 3), dim3(256), 0, stream>>>(
        xb, Wqt, Wkt, Wvt, bq, bk, bv, Qb, Kb, Vb, presentK, presentV);
    k_attn<<<dim3(1024), dim3(256), 0, stream>>>(Qb, Kb, Vb, Ab);
    k_gemm_o<<<dim3(8, 32), dim3(256), 0, stream>>>(Ab, Wot, bo, out);
}

// Round 5
// 180.789 us; speedup vs baseline: 1.0646x; 1.0646x over previous
//
#include <hip/hip_runtime.h>
#include <hip/hip_bf16.h>

typedef __attribute__((ext_vector_type(8))) short short8;
typedef __attribute__((ext_vector_type(4))) short short4v;
typedef __attribute__((ext_vector_type(4))) float f32x4;

#define S_LEN 2048
#define DM 1024
#define NH 16
#define HD 64

__device__ __forceinline__ short f2b(float f) {
    __hip_bfloat16 h = __float2bfloat16(f);
    return *reinterpret_cast<short*>(&h);
}

// ---------------- convert x (fp32 -> bf16) ----------------
__global__ void k_convert_x(const float* __restrict__ x, short* __restrict__ xb) {
    size_t i = ((size_t)blockIdx.x * blockDim.x + threadIdx.x) * 4;
    f32x4 v = *reinterpret_cast<const f32x4*>(x + i);
    short4v o;
    for (int e = 0; e < 4; e++) o[e] = f2b(v[e]);
    *reinterpret_cast<short4v*>(xb + i) = o;
}

// ---------------- transpose + convert W (fp32 [K][N] -> bf16 [N][K]) ----------------
__global__ void k_transpose_w(const float* __restrict__ W, short* __restrict__ Wt) {
    __shared__ float tile[32][33];
    int tx = threadIdx.x, ty = threadIdx.y;
    int nb = blockIdx.x * 32, kb = blockIdx.y * 32;
    for (int i = 0; i < 4; i++)
        tile[ty + i * 8][tx] = W[(size_t)(kb + ty + i * 8) * DM + nb + tx];
    __syncthreads();
    for (int i = 0; i < 4; i++)
        Wt[(size_t)(nb + ty + i * 8) * DM + kb + tx] = f2b(tile[tx][ty + i * 8]);
}

// ---------------- fused QKV GEMM: C = xb @ W + bias  (R3-proven reg staging) ----------------
// Q is scaled by (1/sqrt(1024)) * log2(e) so attention softmax can use exp2.
__global__ __launch_bounds__(256) void k_gemm_qkv(
    const short* __restrict__ xb,
    const short* __restrict__ Wqt, const short* __restrict__ Wkt, const short* __restrict__ Wvt,
    const float* __restrict__ bq, const float* __restrict__ bk, const float* __restrict__ bv,
    short* __restrict__ Qb, short* __restrict__ Kb, short* __restrict__ Vb,
    float* __restrict__ pK, float* __restrict__ pV)
{
    __shared__ alignas(16) short As[128][72];
    __shared__ alignas(16) short Bs[128][72];
    const int z = blockIdx.z;
    const short* Wt  = (z == 0) ? Wqt : (z == 1) ? Wkt : Wvt;
    const float* bias = (z == 0) ? bq : (z == 1) ? bk : bv;
    short* Cb = (z == 0) ? Qb : (z == 1) ? Kb : Vb;
    float* Cf = (z == 1) ? pK : pV;
    const int t = threadIdx.x;
    const int brow = blockIdx.y * 128, bcol = blockIdx.x * 128;
    const int w = t >> 6, l = t & 63;
    const int wr = w >> 1, wc = w & 1;
    const int lr = l & 15, lg = l >> 4;
    f32x4 acc[4][4];
    for (int m = 0; m < 4; m++) for (int n = 0; n < 4; n++) acc[m][n] = (f32x4)0.0f;

    for (int k0 = 0; k0 < DM; k0 += 64) {
        __syncthreads();
        for (int i = 0; i < 4; i++) {
            int idx = i * 256 + t;
            int r = idx >> 3, c8 = (idx & 7) * 8;
            *reinterpret_cast<short8*>(&As[r][c8]) =
                *reinterpret_cast<const short8*>(&xb[(size_t)(brow + r) * DM + k0 + c8]);
            *reinterpret_cast<short8*>(&Bs[r][c8]) =
                *reinterpret_cast<const short8*>(&Wt[(size_t)(bcol + r) * DM + k0 + c8]);
        }
        __syncthreads();
        for (int ks = 0; ks < 2; ks++) {
            short8 a[4], bb[4];
            const int kk = ks * 32 + lg * 8;
            for (int m = 0; m < 4; m++)
                a[m] = *reinterpret_cast<const short8*>(&As[wr * 64 + m * 16 + lr][kk]);
            for (int n = 0; n < 4; n++)
                bb[n] = *reinterpret_cast<const short8*>(&Bs[wc * 64 + n * 16 + lr][kk]);
            for (int m = 0; m < 4; m++)
                for (int n = 0; n < 4; n++)
                    acc[m][n] = __builtin_amdgcn_mfma_f32_16x16x32_bf16(a[m], bb[n], acc[m][n], 0, 0, 0);
        }
    }
    for (int m = 0; m < 4; m++)
        for (int n = 0; n < 4; n++) {
            int row = brow + wr * 64 + m * 16 + lg * 4;
            int col = bcol + wc * 64 + n * 16 + lr;
            float bv_ = bias[col];
            for (int r = 0; r < 4; r++) {
                int rr = row + r;
                float v = acc[m][n][r] + bv_;
                if (z == 0) {
                    Cb[(size_t)rr * DM + col] = f2b(v * 0.0450842200575152f);  // 1/32 * log2(e)
                } else {
                    Cb[(size_t)rr * DM + col] = f2b(v);
                    int b_ = rr >> 11, sI = rr & 2047, hI = col >> 6, dh = col & 63;
                    Cf[(((size_t)(b_ * NH + hI)) * S_LEN + sI) * HD + dh] = v;
                }
            }
        }
}

// ---------------- final GEMM: out = attn @ Wo + bo  (R3-proven) ----------------
__global__ __launch_bounds__(256) void k_gemm_o(
    const short* __restrict__ Ab, const short* __restrict__ Wot,
    const float* __restrict__ bo, float* __restrict__ out)
{
    __shared__ alignas(16) short As[128][72];
    __shared__ alignas(16) short Bs[128][72];
    const int t = threadIdx.x;
    const int brow = blockIdx.y * 128, bcol = blockIdx.x * 128;
    const int w = t >> 6, l = t & 63;
    const int wr = w >> 1, wc = w & 1;
    const int lr = l & 15, lg = l >> 4;
    f32x4 acc[4][4];
    for (int m = 0; m < 4; m++) for (int n = 0; n < 4; n++) acc[m][n] = (f32x4)0.0f;

    for (int k0 = 0; k0 < DM; k0 += 64) {
        __syncthreads();
        for (int i = 0; i < 4; i++) {
            int idx = i * 256 + t;
            int r = idx >> 3, c8 = (idx & 7) * 8;
            *reinterpret_cast<short8*>(&As[r][c8]) =
                *reinterpret_cast<const short8*>(&Ab[(size_t)(brow + r) * DM + k0 + c8]);
            *reinterpret_cast<short8*>(&Bs[r][c8]) =
                *reinterpret_cast<const short8*>(&Wot[(size_t)(bcol + r) * DM + k0 + c8]);
        }
        __syncthreads();
        for (int ks = 0; ks < 2; ks++) {
            short8 a[4], bb[4];
            const int kk = ks * 32 + lg * 8;
            for (int m = 0; m < 4; m++)
                a[m] = *reinterpret_cast<const short8*>(&As[wr * 64 + m * 16 + lr][kk]);
            for (int n = 0; n < 4; n++)
                bb[n] = *reinterpret_cast<const short8*>(&Bs[wc * 64 + n * 16 + lr][kk]);
            for (int m = 0; m < 4; m++)
                for (int n = 0; n < 4; n++)
                    acc[m][n] = __builtin_amdgcn_mfma_f32_16x16x32_bf16(a[m], bb[n], acc[m][n], 0, 0, 0);
        }
    }
    for (int m = 0; m < 4; m++)
        for (int n = 0; n < 4; n++) {
            int row = brow + wr * 64 + m * 16 + lg * 4;
            int col = bcol + wc * 64 + n * 16 + lr;
            float bv_ = bo[col];
            for (int r = 0; r < 4; r++)
                out[(size_t)(row + r) * DM + col] = acc[m][n][r] + bv_;
        }
}

// ---------------- causal flash attention ----------------
// grid 1024, one q-tile per block, descending-qt dispatch (LPT balance).
// NO min-occupancy launch bound: VGPR ~116 <= 128 already allows 16 waves/CU.
__global__ __launch_bounds__(256) void k_attn(
    const short* __restrict__ Qb, const short* __restrict__ Kb,
    const short* __restrict__ Vb, short* __restrict__ Ab)
{
    __shared__ alignas(16) short Vt[64][72];
    __shared__ alignas(16) short Pl[4][16][72];
    const int bid = blockIdx.x;
    const int qt = 31 - (bid >> 5);           // heaviest blocks dispatch first
    const int bh = bid & 31;                  // 4 (b,h) pairs per XCD -> K/V L2-resident
    const int h = bh & 15, b = bh >> 4;
    const int t = threadIdx.x, w = t >> 6, l = t & 63;
    const int lr = l & 15, lg = l >> 4;
    const size_t base = (size_t)b * S_LEN * DM + (size_t)h * HD;
    const short* Qp = Qb + base;
    const short* Kp = Kb + base;
    const short* Vp = Vb + base;

    const int kk0 = t >> 3, d00 = (t & 7) * 8;
    const int kk1 = 32 + (t >> 3);

    const int qbase = qt * 64 + w * 16;
    short8 qf0 = *reinterpret_cast<const short8*>(Qp + (size_t)(qbase + lr) * DM + lg * 8);
    short8 qf1 = *reinterpret_cast<const short8*>(Qp + (size_t)(qbase + lr) * DM + 32 + lg * 8);
    f32x4 o[4];
    for (int dg = 0; dg < 4; dg++) o[dg] = (f32x4)0.0f;
    float mrun[4], lrun[4];
    for (int r = 0; r < 4; r++) { mrun[r] = -INFINITY; lrun[r] = 0.0f; }

    // prologue: prefetch tile 0 (V rows + K fragments) into registers
    short8 vr0 = *reinterpret_cast<const short8*>(Vp + (size_t)kk0 * DM + d00);
    short8 vr1 = *reinterpret_cast<const short8*>(Vp + (size_t)kk1 * DM + d00);
    short8 vn0 = vr0, vn1 = vr1;
    short8 kc[2][4];
#pragma unroll
    for (int ks = 0; ks < 2; ks++)
#pragma unroll
        for (int cg = 0; cg < 4; cg++)
            kc[ks][cg] = *reinterpret_cast<const short8*>(
                Kp + (size_t)(cg * 16 + lr) * DM + ks * 32 + lg * 8);

    for (int j = 0; j <= qt; ++j) {
        const int kbase = j * 64;
        __syncthreads();
#pragma unroll
        for (int e = 0; e < 8; e++) {     // swizzled-transposed V scatter (R3-proven)
            int row = d00 + e;
            int sw = (row >> 3) & 7;
            Vt[row][(((kk0 >> 3) ^ sw) << 3) | (kk0 & 7)] = vr0[e];
            Vt[row][(((kk1 >> 3) ^ sw) << 3) | (kk1 & 7)] = vr1[e];
        }
        __syncthreads();
        if (j < qt) {
            const int kb2 = kbase + 64;
            vn0 = *reinterpret_cast<const short8*>(Vp + (size_t)(kb2 + kk0) * DM + d00);
            vn1 = *reinterpret_cast<const short8*>(Vp + (size_t)(kb2 + kk1) * DM + d00);
        }
        // ---- QK^T ----
        f32x4 s[4];
#pragma unroll
        for (int cg = 0; cg < 4; cg++) s[cg] = (f32x4)0.0f;
#pragma unroll
        for (int ks = 0; ks < 2; ks++) {
            const short8 qf = ks ? qf1 : qf0;
#pragma unroll
            for (int cg = 0; cg < 4; cg++)
                s[cg] = __builtin_amdgcn_mfma_f32_16x16x32_bf16(qf, kc[ks][cg], s[cg], 0, 0, 0);
        }
        if (j < qt) {
            const int kb2 = kbase + 64;
#pragma unroll
            for (int ks = 0; ks < 2; ks++)
#pragma unroll
                for (int cg = 0; cg < 4; cg++)
                    kc[ks][cg] = *reinterpret_cast<const short8*>(
                        Kp + (size_t)(kb2 + cg * 16 + lr) * DM + ks * 32 + lg * 8);
        }
        if (j == qt) {  // causal mask on diagonal tile
#pragma unroll
            for (int cg = 0; cg < 4; cg++)
#pragma unroll
                for (int r = 0; r < 4; r++) {
                    int key = kbase + cg * 16 + lr;
                    int q   = qbase + lg * 4 + r;
                    if (key > q) s[cg][r] = -INFINITY;
                }
        }
        // ---- online softmax in exp2 domain (scores pre-scaled by log2e) ----
        float vmax[4];
#pragma unroll
        for (int r = 0; r < 4; r++) {
            float v = fmaxf(fmaxf(s[0][r], s[1][r]), fmaxf(s[2][r], s[3][r]));
#pragma unroll
            for (int mk = 1; mk < 16; mk <<= 1) v = fmaxf(v, __shfl_xor(v, mk, 16));
            vmax[r] = v;
        }
        bool ok = true;
#pragma unroll
        for (int r = 0; r < 4; r++) ok = ok && (vmax[r] - mrun[r] <= 8.0f);
        if (!__all(ok)) {   // rescale only when the running max grew materially (T13)
            float scl[4];
#pragma unroll
            for (int r = 0; r < 4; r++) {
                float mn = fmaxf(mrun[r], vmax[r]);
                scl[r] = exp2f(mrun[r] - mn);
                mrun[r] = mn;
                lrun[r] *= scl[r];
            }
#pragma unroll
            for (int dg = 0; dg < 4; dg++)
#pragma unroll
                for (int r = 0; r < 4; r++) o[dg][r] *= scl[r];
        }
        float rs[4] = {0.f, 0.f, 0.f, 0.f};
#pragma unroll
        for (int cg = 0; cg < 4; cg++)
#pragma unroll
            for (int r = 0; r < 4; r++) {
                float p = exp2f(s[cg][r] - mrun[r]);
                s[cg][r] = p;
                rs[r] += p;
            }
#pragma unroll
        for (int r = 0; r < 4; r++) {
            float v = rs[r];
#pragma unroll
            for (int mk = 1; mk < 16; mk <<= 1) v += __shfl_xor(v, mk, 16);
            lrun[r] += v;
        }
        // ---- P -> LDS (C/D layout) -> A-fragments ----
#pragma unroll
        for (int cg = 0; cg < 4; cg++)
#pragma unroll
            for (int r = 0; r < 4; r++)
                Pl[w][lg * 4 + r][cg * 16 + lr] = f2b(s[cg][r]);
        short8 pf0 = *reinterpret_cast<const short8*>(&Pl[w][lr][lg * 8]);
        short8 pf1 = *reinterpret_cast<const short8*>(&Pl[w][lr][32 + lg * 8]);
        // ---- PV from swizzled Vt ----
#pragma unroll
        for (int ks = 0; ks < 2; ks++) {
            const short8 pf = ks ? pf1 : pf0;
#pragma unroll
            for (int dg = 0; dg < 4; dg++) {
                int row = dg * 16 + lr;
                int g2 = (ks * 4 + lg) ^ ((row >> 3) & 7);
                short8 vf = *reinterpret_cast<const short8*>(&Vt[row][g2 * 8]);
                o[dg] = __builtin_amdgcn_mfma_f32_16x16x32_bf16(pf, vf, o[dg], 0, 0, 0);
            }
        }
        vr0 = vn0; vr1 = vn1;
    }
    short* Ap = Ab + base;
#pragma unroll
    for (int dg = 0; dg < 4; dg++)
#pragma unroll
        for (int r = 0; r < 4; r++) {
            int q = qbase + lg * 4 + r;
            float v = o[dg][r] / lrun[r];
            Ap[(size_t)q * DM + dg * 16 + lr] = f2b(v);
        }
}

extern "C" void kernel_launch(void* const* d_in, const int* in_sizes, int n_in,
                              void* d_out, int out_size, void* d_ws, size_t ws_size,
                              hipStream_t stream) {
    const float* x  = (const float*)d_in[0];
    const float* Wq = (const float*)d_in[1];
    const float* bq = (const float*)d_in[2];
    const float* Wk = (const float*)d_in[3];
    const float* bk = (const float*)d_in[4];
    const float* Wv = (const float*)d_in[5];
    const float* bv = (const float*)d_in[6];
    const float* Wo = (const float*)d_in[7];
    const float* bo = (const float*)d_in[8];

    float* out = (float*)d_out;
    float* presentK = out + (size_t)4194304;
    float* presentV = presentK + (size_t)4194304;

    char* ws = (char*)d_ws;
    short* xb  = (short*)(ws);
    short* Wqt = (short*)(ws + ((size_t)8  << 20));
    short* Wkt = (short*)(ws + ((size_t)10 << 20));
    short* Wvt = (short*)(ws + ((size_t)12 << 20));
    short* Wot = (short*)(ws + ((size_t)14 << 20));
    short* Qb  = (short*)(ws + ((size_t)16 << 20));
    short* Kb  = (short*)(ws + ((size_t)24 << 20));
    short* Vb  = (short*)(ws + ((size_t)32 << 20));
    short* Ab  = (short*)(ws + ((size_t)40 << 20));

    k_convert_x<<<dim3(4096), dim3(256), 0, stream>>>(x, xb);
    k_transpose_w<<<dim3(32, 32), dim3(32, 8), 0, stream>>>(Wq, Wqt);
    k_transpose_w<<<dim3(32, 32), dim3(32, 8), 0, stream>>>(Wk, Wkt);
    k_transpose_w<<<dim3(32, 32), dim3(32, 8), 0, stream>>>(Wv, Wvt);
    k_transpose_w<<<dim3(32, 32), dim3(32, 8), 0, stream>>>(Wo, Wot);
    k_gemm_qkv<<<dim3(8, 32, 3), dim3(256), 0, stream>>>(
        xb, Wqt, Wkt, Wvt, bq, bk, bv, Qb, Kb, Vb, presentK, presentV);
    k_attn<<<dim3(1024), dim3(256), 0, stream>>>(Qb, Kb, Vb, Ab);
    k_gemm_o<<<dim3(8, 32), dim3(256), 0, stream>>>(Ab, Wot, bo, out);
}

// Round 6
// 157.839 us; speedup vs baseline: 1.2194x; 1.1454x over previous
//
#include <hip/hip_runtime.h>
#include <hip/hip_bf16.h>

typedef __attribute__((ext_vector_type(8))) short short8;
typedef __attribute__((ext_vector_type(4))) short short4v;
typedef __attribute__((ext_vector_type(4))) float f32x4;

#define S_LEN 2048
#define DM 1024
#define NH 16
#define HD 64

__device__ __forceinline__ short f2b(float f) {
    __hip_bfloat16 h = __float2bfloat16(f);
    return *reinterpret_cast<short*>(&h);
}

// ---------------- convert x (fp32 -> bf16) ----------------
__global__ void k_convert_x(const float* __restrict__ x, short* __restrict__ xb) {
    size_t i = ((size_t)blockIdx.x * blockDim.x + threadIdx.x) * 4;
    f32x4 v = *reinterpret_cast<const f32x4*>(x + i);
    short4v o;
    for (int e = 0; e < 4; e++) o[e] = f2b(v[e]);
    *reinterpret_cast<short4v*>(xb + i) = o;
}

// ---------------- transpose + convert W (fp32 [K][N] -> bf16 [N][K]) ----------------
__global__ void k_transpose_w(const float* __restrict__ W, short* __restrict__ Wt) {
    __shared__ float tile[32][33];
    int tx = threadIdx.x, ty = threadIdx.y;
    int nb = blockIdx.x * 32, kb = blockIdx.y * 32;
    for (int i = 0; i < 4; i++)
        tile[ty + i * 8][tx] = W[(size_t)(kb + ty + i * 8) * DM + nb + tx];
    __syncthreads();
    for (int i = 0; i < 4; i++)
        Wt[(size_t)(nb + ty + i * 8) * DM + kb + tx] = f2b(tile[tx][ty + i * 8]);
}

// ---------------- fused QKV GEMM: C = xb @ W + bias  (R3-proven reg staging) ----------------
// Q is scaled by (1/sqrt(1024)) * log2(e) so attention softmax can use exp2.
__global__ __launch_bounds__(256) void k_gemm_qkv(
    const short* __restrict__ xb,
    const short* __restrict__ Wqt, const short* __restrict__ Wkt, const short* __restrict__ Wvt,
    const float* __restrict__ bq, const float* __restrict__ bk, const float* __restrict__ bv,
    short* __restrict__ Qb, short* __restrict__ Kb, short* __restrict__ Vb,
    float* __restrict__ pK, float* __restrict__ pV)
{
    __shared__ alignas(16) short As[128][72];
    __shared__ alignas(16) short Bs[128][72];
    const int z = blockIdx.z;
    const short* Wt  = (z == 0) ? Wqt : (z == 1) ? Wkt : Wvt;
    const float* bias = (z == 0) ? bq : (z == 1) ? bk : bv;
    short* Cb = (z == 0) ? Qb : (z == 1) ? Kb : Vb;
    float* Cf = (z == 1) ? pK : pV;
    const int t = threadIdx.x;
    const int brow = blockIdx.y * 128, bcol = blockIdx.x * 128;
    const int w = t >> 6, l = t & 63;
    const int wr = w >> 1, wc = w & 1;
    const int lr = l & 15, lg = l >> 4;
    f32x4 acc[4][4];
    for (int m = 0; m < 4; m++) for (int n = 0; n < 4; n++) acc[m][n] = (f32x4)0.0f;

    for (int k0 = 0; k0 < DM; k0 += 64) {
        __syncthreads();
        for (int i = 0; i < 4; i++) {
            int idx = i * 256 + t;
            int r = idx >> 3, c8 = (idx & 7) * 8;
            *reinterpret_cast<short8*>(&As[r][c8]) =
                *reinterpret_cast<const short8*>(&xb[(size_t)(brow + r) * DM + k0 + c8]);
            *reinterpret_cast<short8*>(&Bs[r][c8]) =
                *reinterpret_cast<const short8*>(&Wt[(size_t)(bcol + r) * DM + k0 + c8]);
        }
        __syncthreads();
        for (int ks = 0; ks < 2; ks++) {
            short8 a[4], bb[4];
            const int kk = ks * 32 + lg * 8;
            for (int m = 0; m < 4; m++)
                a[m] = *reinterpret_cast<const short8*>(&As[wr * 64 + m * 16 + lr][kk]);
            for (int n = 0; n < 4; n++)
                bb[n] = *reinterpret_cast<const short8*>(&Bs[wc * 64 + n * 16 + lr][kk]);
            for (int m = 0; m < 4; m++)
                for (int n = 0; n < 4; n++)
                    acc[m][n] = __builtin_amdgcn_mfma_f32_16x16x32_bf16(a[m], bb[n], acc[m][n], 0, 0, 0);
        }
    }
    for (int m = 0; m < 4; m++)
        for (int n = 0; n < 4; n++) {
            int row = brow + wr * 64 + m * 16 + lg * 4;
            int col = bcol + wc * 64 + n * 16 + lr;
            float bv_ = bias[col];
            for (int r = 0; r < 4; r++) {
                int rr = row + r;
                float v = acc[m][n][r] + bv_;
                if (z == 0) {
                    Cb[(size_t)rr * DM + col] = f2b(v * 0.0450842200575152f);  // 1/32 * log2(e)
                } else {
                    Cb[(size_t)rr * DM + col] = f2b(v);
                    int b_ = rr >> 11, sI = rr & 2047, hI = col >> 6, dh = col & 63;
                    Cf[(((size_t)(b_ * NH + hI)) * S_LEN + sI) * HD + dh] = v;
                }
            }
        }
}

// ---------------- final GEMM: out = attn @ Wo + bo  (R3-proven) ----------------
__global__ __launch_bounds__(256) void k_gemm_o(
    const short* __restrict__ Ab, const short* __restrict__ Wot,
    const float* __restrict__ bo, float* __restrict__ out)
{
    __shared__ alignas(16) short As[128][72];
    __shared__ alignas(16) short Bs[128][72];
    const int t = threadIdx.x;
    const int brow = blockIdx.y * 128, bcol = blockIdx.x * 128;
    const int w = t >> 6, l = t & 63;
    const int wr = w >> 1, wc = w & 1;
    const int lr = l & 15, lg = l >> 4;
    f32x4 acc[4][4];
    for (int m = 0; m < 4; m++) for (int n = 0; n < 4; n++) acc[m][n] = (f32x4)0.0f;

    for (int k0 = 0; k0 < DM; k0 += 64) {
        __syncthreads();
        for (int i = 0; i < 4; i++) {
            int idx = i * 256 + t;
            int r = idx >> 3, c8 = (idx & 7) * 8;
            *reinterpret_cast<short8*>(&As[r][c8]) =
                *reinterpret_cast<const short8*>(&Ab[(size_t)(brow + r) * DM + k0 + c8]);
            *reinterpret_cast<short8*>(&Bs[r][c8]) =
                *reinterpret_cast<const short8*>(&Wot[(size_t)(bcol + r) * DM + k0 + c8]);
        }
        __syncthreads();
        for (int ks = 0; ks < 2; ks++) {
            short8 a[4], bb[4];
            const int kk = ks * 32 + lg * 8;
            for (int m = 0; m < 4; m++)
                a[m] = *reinterpret_cast<const short8*>(&As[wr * 64 + m * 16 + lr][kk]);
            for (int n = 0; n < 4; n++)
                bb[n] = *reinterpret_cast<const short8*>(&Bs[wc * 64 + n * 16 + lr][kk]);
            for (int m = 0; m < 4; m++)
                for (int n = 0; n < 4; n++)
                    acc[m][n] = __builtin_amdgcn_mfma_f32_16x16x32_bf16(a[m], bb[n], acc[m][n], 0, 0, 0);
        }
    }
    for (int m = 0; m < 4; m++)
        for (int n = 0; n < 4; n++) {
            int row = brow + wr * 64 + m * 16 + lg * 4;
            int col = bcol + wc * 64 + n * 16 + lr;
            float bv_ = bo[col];
            for (int r = 0; r < 4; r++)
                out[(size_t)(row + r) * DM + col] = acc[m][n][r] + bv_;
        }
}

// ---------------- causal flash attention (swapped-operand, in-register softmax) ----------------
// grid 512, R3-proven pair tiling: block does q-tiles (bx, 31-bx) = uniform 33 tiles.
// S^T = mfma(K_frag, Q_frag): lane owns q-row (lane&15); K rows staged at permuted
// physical slots L(p) so post-softmax P is ALREADY in PV's B-fragment order (no LDS, no shfl).
__global__ __launch_bounds__(256) void k_attn(
    const short* __restrict__ Qb, const short* __restrict__ Kb,
    const short* __restrict__ Vb, short* __restrict__ Ab)
{
    __shared__ alignas(16) short Vt[64][72];
    const int bid = blockIdx.x;
    const int orig = (bid & 7) * 64 + (bid >> 3);    // XCD-chunked: 4 (b,h) pairs per XCD
    const int bx = orig & 15, h = (orig >> 4) & 15, b = orig >> 8;
    const int t = threadIdx.x, w = t >> 6, l = t & 63;
    const int lr = l & 15, lg = l >> 4;
    const size_t base = (size_t)b * S_LEN * DM + (size_t)h * HD;
    const short* Qp = Qb + base;
    const short* Kp = Kb + base;
    const short* Vp = Vb + base;

    // V staging map (R3-proven): idx0 = t (keys 0..31), idx1 = 256+t (keys 32..63)
    const int kk0 = t >> 3, d00 = (t & 7) * 8;
    const int kk1 = 32 + (t >> 3);
    // K permutation: physical slot p=cg*16+lr holds logical key (cg>>1)*32+(cg&1)*4+lperm
    const int lperm = (lr >> 2) * 8 + (lr & 3);

    for (int phase = 0; phase < 2; ++phase) {
        const int qt = phase ? 31 - bx : bx;
        const int qbase = qt * 64 + w * 16;
        const int qrow = qbase + lr;                 // this lane's q-row
        short8 qf0 = *reinterpret_cast<const short8*>(Qp + (size_t)qrow * DM + lg * 8);
        short8 qf1 = *reinterpret_cast<const short8*>(Qp + (size_t)qrow * DM + 32 + lg * 8);
        f32x4 o[4];
#pragma unroll
        for (int dg = 0; dg < 4; dg++) o[dg] = (f32x4)0.0f;
        float mrun = -INFINITY, lrun = 0.0f;

        // prologue: prefetch tile 0 (V rows + permuted K fragments)
        short8 vr0 = *reinterpret_cast<const short8*>(Vp + (size_t)kk0 * DM + d00);
        short8 vr1 = *reinterpret_cast<const short8*>(Vp + (size_t)kk1 * DM + d00);
        short8 vn0 = vr0, vn1 = vr1;
        short8 kc[2][4];
#pragma unroll
        for (int ks = 0; ks < 2; ks++)
#pragma unroll
            for (int cg = 0; cg < 4; cg++)
                kc[ks][cg] = *reinterpret_cast<const short8*>(
                    Kp + (size_t)((cg >> 1) * 32 + (cg & 1) * 4 + lperm) * DM + ks * 32 + lg * 8);

        for (int j = 0; j <= qt; ++j) {
            const int kbase = j * 64;
            __syncthreads();
#pragma unroll
            for (int e = 0; e < 8; e++) {   // swizzled-transposed V scatter (R3-proven)
                int row = d00 + e;
                int sw = (row >> 3) & 7;
                Vt[row][(((kk0 >> 3) ^ sw) << 3) | (kk0 & 7)] = vr0[e];
                Vt[row][(((kk1 >> 3) ^ sw) << 3) | (kk1 & 7)] = vr1[e];
            }
            __syncthreads();
            if (j < qt) {
                const int kb2 = kbase + 64;
                vn0 = *reinterpret_cast<const short8*>(Vp + (size_t)(kb2 + kk0) * DM + d00);
                vn1 = *reinterpret_cast<const short8*>(Vp + (size_t)(kb2 + kk1) * DM + d00);
            }
            // ---- swapped QK^T: S^T[key][q] ----
            f32x4 s[4];
#pragma unroll
            for (int cg = 0; cg < 4; cg++) s[cg] = (f32x4)0.0f;
#pragma unroll
            for (int ks = 0; ks < 2; ks++) {
                const short8 qf = ks ? qf1 : qf0;
#pragma unroll
                for (int cg = 0; cg < 4; cg++)
                    s[cg] = __builtin_amdgcn_mfma_f32_16x16x32_bf16(kc[ks][cg], qf, s[cg], 0, 0, 0);
            }
            if (j < qt) {  // prefetch next permuted K tile
                const int kb2 = kbase + 64;
#pragma unroll
                for (int ks = 0; ks < 2; ks++)
#pragma unroll
                    for (int cg = 0; cg < 4; cg++)
                        kc[ks][cg] = *reinterpret_cast<const short8*>(
                            Kp + (size_t)(kb2 + (cg >> 1) * 32 + (cg & 1) * 4 + lperm) * DM + ks * 32 + lg * 8);
            }
            if (j == qt) {  // causal mask: s[cg][r] is logical key (cg>>1)*32+lg*8+(cg&1)*4+r
#pragma unroll
                for (int cg = 0; cg < 4; cg++)
#pragma unroll
                    for (int r = 0; r < 4; r++) {
                        int n = ((cg >> 1) << 5) + (lg << 3) + ((cg & 1) << 2) + r;
                        if (kbase + n > qrow) s[cg][r] = -INFINITY;
                    }
            }
            // ---- in-register online softmax (exp2 domain; scores pre-scaled by log2e) ----
            float mx0 = fmaxf(fmaxf(s[0][0], s[0][1]), fmaxf(s[0][2], s[0][3]));
            float mx1 = fmaxf(fmaxf(s[1][0], s[1][1]), fmaxf(s[1][2], s[1][3]));
            float mx2 = fmaxf(fmaxf(s[2][0], s[2][1]), fmaxf(s[2][2], s[2][3]));
            float mx3 = fmaxf(fmaxf(s[3][0], s[3][1]), fmaxf(s[3][2], s[3][3]));
            float vmax = fmaxf(fmaxf(mx0, mx1), fmaxf(mx2, mx3));
            vmax = fmaxf(vmax, __shfl_xor(vmax, 16));
            vmax = fmaxf(vmax, __shfl_xor(vmax, 32));
            if (!__all(vmax - mrun <= 8.0f)) {   // defer-max (T13)
                float mn = fmaxf(mrun, vmax);
                float scl = exp2f(mrun - mn);
                mrun = mn; lrun *= scl;
#pragma unroll
                for (int dg = 0; dg < 4; dg++)
#pragma unroll
                    for (int r = 0; r < 4; r++) o[dg][r] *= scl;
            }
            float rs = 0.0f;
#pragma unroll
            for (int cg = 0; cg < 4; cg++)
#pragma unroll
                for (int r = 0; r < 4; r++) {
                    float p = exp2f(s[cg][r] - mrun);
                    s[cg][r] = p;
                    rs += p;
                }
            rs += __shfl_xor(rs, 16);
            rs += __shfl_xor(rs, 32);
            lrun += rs;
            // ---- P already in B-fragment order: pure in-lane pack ----
            short8 pf0, pf1;
#pragma unroll
            for (int r = 0; r < 4; r++) {
                pf0[r] = f2b(s[0][r]); pf0[4 + r] = f2b(s[1][r]);
                pf1[r] = f2b(s[2][r]); pf1[4 + r] = f2b(s[3][r]);
            }
            // ---- PV: O^T[d][q] = mfma(V_frag, P_frag) from swizzled Vt ----
#pragma unroll
            for (int ks = 0; ks < 2; ks++) {
                const short8 pf = ks ? pf1 : pf0;
#pragma unroll
                for (int dg = 0; dg < 4; dg++) {
                    int row = dg * 16 + lr;
                    int g2 = (ks * 4 + lg) ^ ((row >> 3) & 7);
                    short8 vf = *reinterpret_cast<const short8*>(&Vt[row][g2 * 8]);
                    o[dg] = __builtin_amdgcn_mfma_f32_16x16x32_bf16(vf, pf, o[dg], 0, 0, 0);
                }
            }
            vr0 = vn0; vr1 = vn1;
        }
        // ---- write O^T: lane holds d = dg*16+lg*4+r for its q-row; packed 8B stores ----
        short* Ap = Ab + base;
        float rinv = 1.0f / lrun;
#pragma unroll
        for (int dg = 0; dg < 4; dg++) {
            short4v ov;
#pragma unroll
            for (int r = 0; r < 4; r++) ov[r] = f2b(o[dg][r] * rinv);
            *reinterpret_cast<short4v*>(Ap + (size_t)qrow * DM + dg * 16 + lg * 4) = ov;
        }
    }
}

extern "C" void kernel_launch(void* const* d_in, const int* in_sizes, int n_in,
                              void* d_out, int out_size, void* d_ws, size_t ws_size,
                              hipStream_t stream) {
    const float* x  = (const float*)d_in[0];
    const float* Wq = (const float*)d_in[1];
    const float* bq = (const float*)d_in[2];
    const float* Wk = (const float*)d_in[3];
    const float* bk = (const float*)d_in[4];
    const float* Wv = (const float*)d_in[5];
    const float* bv = (const float*)d_in[6];
    const float* Wo = (const float*)d_in[7];
    const float* bo = (const float*)d_in[8];

    float* out = (float*)d_out;
    float* presentK = out + (size_t)4194304;
    float* presentV = presentK + (size_t)4194304;

    char* ws = (char*)d_ws;
    short* xb  = (short*)(ws);
    short* Wqt = (short*)(ws + ((size_t)8  << 20));
    short* Wkt = (short*)(ws + ((size_t)10 << 20));
    short* Wvt = (short*)(ws + ((size_t)12 << 20));
    short* Wot = (short*)(ws + ((size_t)14 << 20));
    short* Qb  = (short*)(ws + ((size_t)16 << 20));
    short* Kb  = (short*)(ws + ((size_t)24 << 20));
    short* Vb  = (short*)(ws + ((size_t)32 << 20));
    short* Ab  = (short*)(ws + ((size_t)40 << 20));

    k_convert_x<<<dim3(4096), dim3(256), 0, stream>>>(x, xb);
    k_transpose_w<<<dim3(32, 32), dim3(32, 8), 0, stream>>>(Wq, Wqt);
    k_transpose_w<<<dim3(32, 32), dim3(32, 8), 0, stream>>>(Wk, Wkt);
    k_transpose_w<<<dim3(32, 32), dim3(32, 8), 0, stream>>>(Wv, Wvt);
    k_transpose_w<<<dim3(32, 32), dim3(32, 8), 0, stream>>>(Wo, Wot);
    k_gemm_qkv<<<dim3(8, 32, 3), dim3(256), 0, stream>>>(
        xb, Wqt, Wkt, Wvt, bq, bk, bv, Qb, Kb, Vb, presentK, presentV);
    k_attn<<<dim3(512), dim3(256), 0, stream>>>(Qb, Kb, Vb, Ab);
    k_gemm_o<<<dim3(8, 32), dim3(256), 0, stream>>>(Ab, Wot, bo, out);
}